// Round 5
// baseline (816.514 us; speedup 1.0000x reference)
//
#include <hip/hip_runtime.h>

#define N_ 768
#define CS 384
#define CZ 128
#define HH 12
#define PQ_ 4
#define PV_ 8

// ---------------------------------------------------------------------------
// K_front: three independent jobs in one dispatch (branch on blockIdx):
//   [0, 9216)      zb:   zbT[n][h][m] = sqrt(1/3)*(z[n,m,:]@w_b[h,:]+b_b[h])
//   [9216, 9792)   proj: all s-projections as permuted-row GEMM (round-4 k_proj)
//   [9792, 10944)  init: out[n][j] = b_out[j]  (atomic base for k_final)
// Shared-LDS union: max 9344 floats = 37.4 KB -> 4 blocks/CU everywhere.
// ---------------------------------------------------------------------------
__global__ __launch_bounds__(256, 4) void k_front(
    const float* __restrict__ s,
    const float* __restrict__ rot,
    const float* __restrict__ trans,
    const float* __restrict__ w_q,  const float* __restrict__ b_q,
    const float* __restrict__ w_kv, const float* __restrict__ b_kv,
    const float* __restrict__ w_qp, const float* __restrict__ b_qp,
    const float* __restrict__ w_kvp,const float* __restrict__ b_kvp,
    const float* __restrict__ z,
    const float* __restrict__ w_b, const float* __restrict__ b_b,
    const float* __restrict__ b_out,
    float* __restrict__ q, float* __restrict__ kT,
    float* __restrict__ qp, float* __restrict__ kpT,
    float* __restrict__ vcat,
    float* __restrict__ zbT,
    float* __restrict__ out)
{
    __shared__ __align__(16) float smem[9344];
    const int bid = blockIdx.x;
    const int tid = threadIdx.x;

    if (bid < 9216) {
        // ================= zb =================
        float* zs  = smem;            // 64*133
        float* zbt = smem + 8512;     // 64*13
        const int n  = bid / 12;
        const int m0 = (bid % 12) * 64;

        const float4* zsrc = (const float4*)(z + ((size_t)n * N_ + m0) * CZ);
        #pragma unroll
        for (int j = 0; j < 8; ++j) {
            int idx = tid + j * 256;
            float4 zv = zsrc[idx];
            int f  = idx << 2;
            int ml = f >> 7;
            int c  = f & 127;
            float* d = &zs[ml * 133 + c];
            d[0] = zv.x; d[1] = zv.y; d[2] = zv.z; d[3] = zv.w;
        }
        __syncthreads();

        const int ml = tid & 63;
        const int hq = __builtin_amdgcn_readfirstlane(tid >> 6);
        const float* w0 = w_b + (hq * 3 + 0) * CZ;
        const float* w1 = w0 + CZ;
        const float* w2 = w1 + CZ;
        const float* zrow = &zs[ml * 133];
        float a0 = 0.f, a1 = 0.f, a2 = 0.f;
        #pragma unroll 8
        for (int c = 0; c < CZ; ++c) {
            float zv = zrow[c];
            a0 += zv * w0[c];
            a1 += zv * w1[c];
            a2 += zv * w2[c];
        }
        const float s3 = 0.5773502691896258f;
        zbt[ml * 13 + hq * 3 + 0] = s3 * (a0 + b_b[hq * 3 + 0]);
        zbt[ml * 13 + hq * 3 + 1] = s3 * (a1 + b_b[hq * 3 + 1]);
        zbt[ml * 13 + hq * 3 + 2] = s3 * (a2 + b_b[hq * 3 + 2]);
        __syncthreads();

        for (int idx = tid; idx < 768; idx += 256) {
            int h = idx >> 6, mm = idx & 63;
            zbT[(size_t)n * (HH * N_) + h * N_ + m0 + mm] = zbt[mm * 13 + h];
        }
    } else if (bid < 9792) {
        // ================= proj =================
        const int b2 = bid - 9216;
        const int rt = b2 % 48;
        const int nt = b2 / 48;
        const int r0 = rt * 24;
        const int n0 = nt * 64;

        float (*Ws)[36] = (float(*)[36])smem;               // 2304
        float (*Ss)[66] = (float(*)[66])(smem + 2304);      // 4224
        float (*Rsh)[9] = (float(*)[9])(smem + 6528);       // 576
        float (*Tsh)[3] = (float(*)[3])(smem + 7104);       // 192
        float* bsh      = smem + 7296;                      // 24

        auto vmap = [&](int rv, const float*& wrow, float& bias) {
            if (rv < 192)      { wrow = w_q + (size_t)rv * CS;  bias = b_q[rv]; }
            else if (rv < 576) { int r = rv - 192; wrow = w_kv + (size_t)r * CS; bias = b_kv[r]; }
            else if (rv < 720) { int t = rv - 576; int hp = t / 3, d = t % 3;
                                 int r = d * 48 + hp;  wrow = w_qp + (size_t)r * CS;  bias = b_qp[r]; }
            else               { int t = rv - 720; int j = t / 3, d = t % 3;
                                 int r = d * 144 + j; wrow = w_kvp + (size_t)r * CS; bias = b_kvp[r]; }
        };

        if (tid < 24) {
            const float* wr; float bb;
            vmap(r0 + tid, wr, bb);
            bsh[tid] = bb;
        }
        if (r0 >= 576) {
            for (int idx = tid; idx < 64 * 9; idx += 256)
                Rsh[idx / 9][idx % 9] = rot[(size_t)(n0 + idx / 9) * 9 + idx % 9];
            for (int idx = tid; idx < 64 * 3; idx += 256)
                Tsh[idx / 3][idx % 3] = trans[(size_t)(n0 + idx / 3) * 3 + idx % 3];
        }

        const int g_n = tid & 31;
        const int g_r = tid >> 5;
        float acc[3][2] = {{0.f,0.f},{0.f,0.f},{0.f,0.f}};

        for (int ks = 0; ks < 6; ++ks) {
            const int kb = ks * 64;
            for (int t4 = tid; t4 < 384; t4 += 256) {
                int rl = t4 >> 4, c4 = t4 & 15;
                const float* wrow; float bb;
                vmap(r0 + rl, wrow, bb);
                float4 wv = *(const float4*)(wrow + kb + c4 * 4);
                int slot = (rl / 3) * 4 + rl % 3;
                Ws[c4 * 4 + 0][slot] = wv.x;
                Ws[c4 * 4 + 1][slot] = wv.y;
                Ws[c4 * 4 + 2][slot] = wv.z;
                Ws[c4 * 4 + 3][slot] = wv.w;
            }
            for (int t4 = tid; t4 < 1024; t4 += 256) {
                int nl = t4 >> 4, c4 = t4 & 15;
                float4 sv = *(const float4*)(s + (size_t)(n0 + nl) * CS + kb + c4 * 4);
                Ss[c4 * 4 + 0][nl] = sv.x;
                Ss[c4 * 4 + 1][nl] = sv.y;
                Ss[c4 * 4 + 2][nl] = sv.z;
                Ss[c4 * 4 + 3][nl] = sv.w;
            }
            __syncthreads();
            #pragma unroll 8
            for (int k = 0; k < 64; ++k) {
                float4 w  = *(const float4*)&Ws[k][g_r * 4];
                float2 sv = *(const float2*)&Ss[k][g_n * 2];
                acc[0][0] += w.x * sv.x;  acc[0][1] += w.x * sv.y;
                acc[1][0] += w.y * sv.x;  acc[1][1] += w.y * sv.y;
                acc[2][0] += w.z * sv.x;  acc[2][1] += w.z * sv.y;
            }
            __syncthreads();
        }

        const float b0 = bsh[g_r * 3 + 0];
        const float b1 = bsh[g_r * 3 + 1];
        const float b2v = bsh[g_r * 3 + 2];
        const int rvb = r0 + g_r * 3;

        if (rvb < 192) {
            #pragma unroll
            for (int nn = 0; nn < 2; ++nn) {
                int n = n0 + g_n * 2 + nn;
                q[(size_t)n * 192 + rvb + 0] = acc[0][nn] + b0;
                q[(size_t)n * 192 + rvb + 1] = acc[1][nn] + b1;
                q[(size_t)n * 192 + rvb + 2] = acc[2][nn] + b2v;
            }
        } else if (rvb < 576) {
            #pragma unroll
            for (int cc = 0; cc < 3; ++cc) {
                int i = rvb + cc - 192;
                int h = i >> 5, c = i & 31;
                float bb = (cc == 0) ? b0 : (cc == 1) ? b1 : b2v;
                if (c < 16) {
                    float2 st = make_float2(acc[cc][0] + bb, acc[cc][1] + bb);
                    *(float2*)&kT[(size_t)(h * 16 + c) * N_ + n0 + g_n * 2] = st;
                } else {
                    vcat[(size_t)(n0 + g_n * 2 + 0) * 480 + h * 16 + c - 16] = acc[cc][0] + bb;
                    vcat[(size_t)(n0 + g_n * 2 + 1) * 480 + h * 16 + c - 16] = acc[cc][1] + bb;
                }
            }
        } else if (rvb < 720) {
            int hp = (rvb - 576) / 3;
            #pragma unroll
            for (int nn = 0; nn < 2; ++nn) {
                int nl = g_n * 2 + nn, n = n0 + nl;
                float x = acc[0][nn] + b0, y = acc[1][nn] + b1, zc = acc[2][nn] + b2v;
                const float* R = Rsh[nl];
                const float* T = Tsh[nl];
                #pragma unroll
                for (int d = 0; d < 3; ++d)
                    qp[(size_t)n * 144 + hp * 3 + d] =
                        R[d * 3 + 0] * x + R[d * 3 + 1] * y + R[d * 3 + 2] * zc + T[d];
            }
        } else {
            int j = (rvb - 720) / 3;
            int h = j / 12, p = j % 12;
            float px[2][3];
            #pragma unroll
            for (int nn = 0; nn < 2; ++nn) {
                int nl = g_n * 2 + nn;
                float x = acc[0][nn] + b0, y = acc[1][nn] + b1, zc = acc[2][nn] + b2v;
                const float* R = Rsh[nl];
                const float* T = Tsh[nl];
                #pragma unroll
                for (int d = 0; d < 3; ++d)
                    px[nn][d] = R[d * 3 + 0] * x + R[d * 3 + 1] * y + R[d * 3 + 2] * zc + T[d];
            }
            if (p < PQ_) {
                #pragma unroll
                for (int d = 0; d < 3; ++d)
                    *(float2*)&kpT[(size_t)(h * 12 + p * 3 + d) * N_ + n0 + g_n * 2] =
                        make_float2(px[0][d], px[1][d]);
            } else {
                int base = 192 + (h * PV_ + p - PQ_) * 3;
                #pragma unroll
                for (int nn = 0; nn < 2; ++nn) {
                    int n = n0 + g_n * 2 + nn;
                    #pragma unroll
                    for (int d = 0; d < 3; ++d)
                        vcat[(size_t)n * 480 + base + d] = px[nn][d];
                }
            }
        }
    } else {
        // ================= init =================
        const int idx = (bid - 9792) * 256 + tid;   // < 294912 = 768*384
        out[idx] = b_out[idx % 384];
    }
}

// ---------------------------------------------------------------------------
// K2 (fused): per residue n — logits, softmax; probs written back into
// zbT[n] (in-place reuse, consumed by k_opair); o + o_pt over vcat columns;
// zeroes ocat[n][576:2112] (atomic base for k_opair); inv-rot + norms.
// ---------------------------------------------------------------------------
__global__ __launch_bounds__(256, 4) void k_fused(
    const float* __restrict__ q, const float* __restrict__ kT,
    const float* __restrict__ qp, const float* __restrict__ kpT,
    const float* __restrict__ vcat,
    float* __restrict__ zbT,
    const float* __restrict__ head_weights,
    const float* __restrict__ mask,
    const float* __restrict__ rot, const float* __restrict__ trans,
    float* __restrict__ ocat)
{
    const int n   = (N_ - 1) - blockIdx.x;
    const int tid = threadIdx.x;

    __shared__ float qv[192], qpt[144];
    __shared__ float hw[HH];
    __shared__ __align__(16) float L[HH * N_];    // 36 KB: logits -> probs
    __shared__ float og[288];
    __shared__ float R[9], T[3];

    for (int i = tid; i < 192; i += 256) qv[i] = q[n * 192 + i];
    for (int i = tid; i < 144; i += 256) qpt[i] = qp[n * 144 + i];
    if (tid < HH) {
        float x = head_weights[tid];
        hw[tid] = 0.13608276348795434f * logf(1.0f + expf(x));
    }
    if (tid < 9) R[tid] = rot[n * 9 + tid];
    if (tid < 3) T[tid] = trans[n * 3 + tid];
    __syncthreads();

    const float mn = mask[n];

    // ---- pass 1: logits (transposed operands, float4 over m) ----
    if (tid < 192) {
        const int m0 = tid * 4;
        float4 mk = *(const float4*)(mask + m0);
        float mt0 = (mn * mk.x - 1.0f) * 100000.0f;
        float mt1 = (mn * mk.y - 1.0f) * 100000.0f;
        float mt2 = (mn * mk.z - 1.0f) * 100000.0f;
        float mt3 = (mn * mk.w - 1.0f) * 100000.0f;
        const float* zbn = zbT + (size_t)n * (HH * N_);
        #pragma unroll
        for (int h = 0; h < HH; ++h) {
            float ax = 0.f, ay = 0.f, az = 0.f, aw = 0.f;
            #pragma unroll
            for (int c = 0; c < 16; ++c) {
                float qc = qv[h * 16 + c];
                float4 kx = *(const float4*)&kT[(size_t)(h * 16 + c) * N_ + m0];
                ax += qc * kx.x; ay += qc * kx.y; az += qc * kx.z; aw += qc * kx.w;
            }
            const float s48 = 0.14433756729740643f;
            ax *= s48; ay *= s48; az *= s48; aw *= s48;
            float4 zb4 = *(const float4*)&zbn[h * N_ + m0];
            ax += zb4.x; ay += zb4.y; az += zb4.z; aw += zb4.w;
            float dx = 0.f, dy = 0.f, dz = 0.f, dw = 0.f;
            #pragma unroll
            for (int pd = 0; pd < 12; ++pd) {
                float qd = qpt[h * 12 + pd];
                float4 kd = *(const float4*)&kpT[(size_t)(h * 12 + pd) * N_ + m0];
                float ex = qd - kd.x, ey = qd - kd.y, ez = qd - kd.z, ew = qd - kd.w;
                dx += ex * ex; dy += ey * ey; dz += ez * ez; dw += ew * ew;
            }
            float hwh = 0.5f * hw[h];
            float4 out;
            out.x = ax - hwh * dx + mt0;
            out.y = ay - hwh * dy + mt1;
            out.z = az - hwh * dz + mt2;
            out.w = aw - hwh * dw + mt3;
            *(float4*)&L[h * N_ + m0] = out;
        }
    }
    __syncthreads();

    // ---- pass 2: softmax per head ----
    {
        const int wv_ = tid >> 6, lane = tid & 63;
        #pragma unroll
        for (int j = 0; j < 3; ++j) {
            const int h = wv_ + 4 * j;
            float vals[12];
            float mx = -1e30f;
            #pragma unroll
            for (int t = 0; t < 12; ++t) {
                vals[t] = L[h * N_ + lane + 64 * t];
                mx = fmaxf(mx, vals[t]);
            }
            #pragma unroll
            for (int off = 32; off; off >>= 1) mx = fmaxf(mx, __shfl_xor(mx, off));
            float sum = 0.f;
            #pragma unroll
            for (int t = 0; t < 12; ++t) { vals[t] = expf(vals[t] - mx); sum += vals[t]; }
            #pragma unroll
            for (int off = 32; off; off >>= 1) sum += __shfl_xor(sum, off);
            float inv = 1.0f / sum;
            #pragma unroll
            for (int t = 0; t < 12; ++t) L[h * N_ + lane + 64 * t] = vals[t] * inv;
        }
    }
    __syncthreads();

    float* oc = ocat + (size_t)n * 2112;

    // ---- spill probs to global (zbT row n, in-place reuse) ----
    {
        float4* dst = (float4*)(zbT + (size_t)n * (HH * N_));
        const float4* src = (const float4*)L;
        for (int i4 = tid; i4 < HH * N_ / 4; i4 += 256) dst[i4] = src[i4];
    }
    // ---- zero o_pair region (atomic base for k_opair) ----
    for (int i = tid; i < HH * CZ; i += 256) oc[576 + i] = 0.f;

    // ---- pass 3: o (192) + o_pt (288) over vcat columns (lane-coalesced) ----
    {
        const int i0 = tid;
        const int i1 = tid + 256;
        const bool act1 = (i1 < 480);
        const int h0 = (i0 < 192) ? (i0 >> 4) : ((i0 - 192) / 24);
        const int h1 = act1 ? ((i1 - 192) / 24) : 0;
        const float* Lh0 = L + h0 * N_;
        const float* Lh1 = L + h1 * N_;
        const float* vc0 = vcat + i0;
        const float* vc1 = vcat + (act1 ? i1 : 0);
        float a0 = 0.f, a1 = 0.f;
        #pragma unroll 8
        for (int m = 0; m < N_; ++m) {
            float x0 = vc0[(size_t)m * 480];
            float x1 = vc1[(size_t)m * 480];
            a0 += Lh0[m] * x0;
            a1 += Lh1[m] * x1;
        }
        if (i0 < 192) oc[i0] = a0; else og[i0 - 192] = a0;
        if (act1) og[i1 - 192] = a1;
    }
    __syncthreads();

    // ---- inverse rotation + norms ----
    for (int hp = tid; hp < 96; hp += 256) {
        float gx = og[hp * 3 + 0] - T[0];
        float gy = og[hp * 3 + 1] - T[1];
        float gz = og[hp * 3 + 2] - T[2];
        float lx = R[0] * gx + R[3] * gy + R[6] * gz;
        float ly = R[1] * gx + R[4] * gy + R[7] * gz;
        float lz = R[2] * gx + R[5] * gy + R[8] * gz;
        oc[192 + hp] = lx;
        oc[288 + hp] = ly;
        oc[384 + hp] = lz;
        oc[480 + hp] = sqrtf(lx * lx + ly * ly + lz * lz + 1e-8f);
    }
}

// ---------------------------------------------------------------------------
// K_opair: ocat[n][576+h*128+c] += sum_m probs[n][h][m] * z[n][m][c]
// grid = 768 n (reverse, LLC-friendly) x 6 m-tiles of 128. Thread =
// (c-quad, m-group of 16). shfl fold + LDS tree + coalesced atomicAdd.
// LDS 30 KB -> 5 blocks/CU.
// ---------------------------------------------------------------------------
__global__ __launch_bounds__(256, 5) void k_opair(
    const float* __restrict__ probs,     // zbT, now holding softmax probs
    const float* __restrict__ z,
    float* __restrict__ ocat)
{
    const int bid = blockIdx.x;           // 768*6
    const int n   = (N_ - 1) - (bid / 6);
    const int mt  = bid % 6;
    const int tid = threadIdx.x;

    __shared__ float Ls[HH][128];         // 6 KB
    __shared__ float4 part[4][HH][32];    // 24 KB

    const float* Lr = probs + (size_t)n * (HH * N_);
    for (int i = tid; i < HH * 128; i += 256)
        Ls[i >> 7][i & 127] = Lr[(i >> 7) * N_ + mt * 128 + (i & 127)];
    __syncthreads();

    const int c4 = tid & 31, g = tid >> 5;
    float4 acc[HH];
    #pragma unroll
    for (int h = 0; h < HH; ++h) { acc[h].x = acc[h].y = acc[h].z = acc[h].w = 0.f; }

    const float4* zr = (const float4*)(z + (size_t)n * N_ * CZ) + c4;
    const int ms = mt * 128 + g * 16;
    #pragma unroll 4
    for (int mm = 0; mm < 16; ++mm) {
        float4 zz = zr[(size_t)(ms + mm) * 32];
        const int ml = g * 16 + mm;
        #pragma unroll
        for (int h = 0; h < HH; ++h) {
            float lh = Ls[h][ml];
            acc[h].x += lh * zz.x; acc[h].y += lh * zz.y;
            acc[h].z += lh * zz.z; acc[h].w += lh * zz.w;
        }
    }
    #pragma unroll
    for (int h = 0; h < HH; ++h) {
        acc[h].x += __shfl_xor(acc[h].x, 32);
        acc[h].y += __shfl_xor(acc[h].y, 32);
        acc[h].z += __shfl_xor(acc[h].z, 32);
        acc[h].w += __shfl_xor(acc[h].w, 32);
    }
    if ((tid & 63) < 32) {
        const int w = tid >> 6;
        #pragma unroll
        for (int h = 0; h < HH; ++h) part[w][h][c4] = acc[h];
    }
    __syncthreads();

    float* oc = ocat + (size_t)n * 2112 + 576;
    const float* p0 = (const float*)part[0];
    const float* p1 = (const float*)part[1];
    const float* p2 = (const float*)part[2];
    const float* p3 = (const float*)part[3];
    for (int i = tid; i < HH * CZ; i += 256)
        atomicAdd(&oc[i], p0[i] + p1[i] + p2[i] + p3[i]);
}

// ---------------------------------------------------------------------------
// K3: out[n][j] += o_cat[n,:kq] . w_out[j,:kq]  (unchanged from round 4)
// ---------------------------------------------------------------------------
__global__ __launch_bounds__(256, 6) void k_final(
    const float* __restrict__ ocat,
    const float* __restrict__ w_out,
    float* __restrict__ out)
{
    const int b  = blockIdx.x;
    const int bk = b & 3;
    const int bn = (b >> 2) % 48;
    const int bj = (b >> 2) / 48;
    const int n0 = bn * 16, j0 = bj * 64, kq0 = bk * 528;
    const int tid = threadIdx.x;

    __shared__ float As_t[48][20];
    __shared__ float Bs[64][49];

    const int tj = tid & 63;
    const int tn = tid >> 6;
    float a0 = 0.f, a1 = 0.f, a2 = 0.f, a3 = 0.f;

    for (int st = 0; st < 11; ++st) {
        const int kb = kq0 + st * 48;
        for (int t4 = tid; t4 < 192; t4 += 256) {
            int nl = t4 / 12, c4 = t4 % 12;
            float4 av = *(const float4*)(ocat + (size_t)(n0 + nl) * 2112 + kb + c4 * 4);
            As_t[c4 * 4 + 0][nl] = av.x;
            As_t[c4 * 4 + 1][nl] = av.y;
            As_t[c4 * 4 + 2][nl] = av.z;
            As_t[c4 * 4 + 3][nl] = av.w;
        }
        for (int t4 = tid; t4 < 768; t4 += 256) {
            int jr = t4 / 12, c4 = t4 % 12;
            float4 wv = *(const float4*)(w_out + (size_t)(j0 + jr) * 2112 + kb + c4 * 4);
            Bs[jr][c4 * 4 + 0] = wv.x;
            Bs[jr][c4 * 4 + 1] = wv.y;
            Bs[jr][c4 * 4 + 2] = wv.z;
            Bs[jr][c4 * 4 + 3] = wv.w;
        }
        __syncthreads();
        #pragma unroll 8
        for (int k = 0; k < 48; ++k) {
            float bb = Bs[tj][k];
            float4 av = *(const float4*)&As_t[k][tn * 4];
            a0 += bb * av.x; a1 += bb * av.y; a2 += bb * av.z; a3 += bb * av.w;
        }
        __syncthreads();
    }

    float* op = out + (size_t)(n0 + tn * 4) * 384 + j0 + tj;
    atomicAdd(op + 0 * 384, a0);
    atomicAdd(op + 1 * 384, a1);
    atomicAdd(op + 2 * 384, a2);
    atomicAdd(op + 3 * 384, a3);
}

extern "C" void kernel_launch(void* const* d_in, const int* in_sizes, int n_in,
                              void* d_out, int out_size, void* d_ws, size_t ws_size,
                              hipStream_t stream)
{
    const float* s     = (const float*)d_in[0];
    const float* z     = (const float*)d_in[1];
    const float* rot   = (const float*)d_in[2];
    const float* trans = (const float*)d_in[3];
    const float* mask  = (const float*)d_in[4];
    const float* w_q   = (const float*)d_in[5];
    const float* b_q   = (const float*)d_in[6];
    const float* w_kv  = (const float*)d_in[7];
    const float* b_kv  = (const float*)d_in[8];
    const float* w_qp  = (const float*)d_in[9];
    const float* b_qp  = (const float*)d_in[10];
    const float* w_kvp = (const float*)d_in[11];
    const float* b_kvp = (const float*)d_in[12];
    const float* w_b   = (const float*)d_in[13];
    const float* b_b   = (const float*)d_in[14];
    const float* hwts  = (const float*)d_in[15];
    const float* w_out = (const float*)d_in[16];
    const float* b_out = (const float*)d_in[17];

    float* ws    = (float*)d_ws;
    float* q     = ws;                    // 768*192      =   147456
    float* kT    = q     + 147456;        // 192*768      =   147456
    float* qp    = kT    + 147456;        // 768*144      =   110592
    float* kpT   = qp    + 110592;        // 144*768      =   110592
    float* vcat  = kpT   + 110592;        // 768*480      =   368640
    float* zbT   = vcat  + 368640;        // 768*12*768   =  7077888 (bias -> probs)
    float* ocat  = zbT   + 7077888;       // 768*2112     =  1622016
    // total: 9,584,640 floats = 38.3 MB

    k_front<<<10944, 256, 0, stream>>>(s, rot, trans, w_q, b_q, w_kv, b_kv,
                                       w_qp, b_qp, w_kvp, b_kvp, z, w_b, b_b,
                                       b_out, q, kT, qp, kpT, vcat, zbT,
                                       (float*)d_out);
    k_fused<<<N_, 256, 0, stream>>>(q, kT, qp, kpT, vcat, zbT,
                                    hwts, mask, rot, trans, ocat);
    k_opair<<<N_ * 6, 256, 0, stream>>>(zbT, z, ocat);
    k_final<<<1152, 256, 0, stream>>>(ocat, w_out, (float*)d_out);
}